// Round 3
// baseline (1006.093 us; speedup 1.0000x reference)
//
#include <hip/hip_runtime.h>

typedef __attribute__((ext_vector_type(8))) __bf16 bf16x8;
typedef __attribute__((ext_vector_type(4))) float floatx4;

#define NN 16384
#define EPS 1e-5f

__device__ __forceinline__ unsigned short f2b(float f) {
  unsigned u = __float_as_uint(f);
  u += 0x7fffu + ((u >> 16) & 1u);
  return (unsigned short)(u >> 16);
}
__device__ __forceinline__ float b2f(unsigned short u) {
  return __uint_as_float(((unsigned)u) << 16);
}

// kept for harness symbol expectations; never launched
__global__ void RoboNodeEncoder_88424786690347_kernel() {}

// ---------------------------------------------------------------- zero init
__global__ __launch_bounds__(256) void zero_u32(unsigned* __restrict__ p, int n) {
  int i = blockIdx.x * blockDim.x + threadIdx.x;
  if (i < n) p[i] = 0u;
}

// -------------------------------------------------------- f32 -> bf16 copy
__global__ __launch_bounds__(256) void convert_f32_b16(const float* __restrict__ in,
                                                       unsigned short* __restrict__ out, int n) {
  int i = blockIdx.x * blockDim.x + threadIdx.x;
  if (i < n) out[i] = f2b(in[i]);
}

// --------------------------------------------------- f32 -> bf16 transpose
// in: [R, C] f32 row-major; out: [C, R] bf16 row-major
__global__ __launch_bounds__(256) void transpose_f32_b16(const float* __restrict__ in,
                                                         unsigned short* __restrict__ out,
                                                         int R, int C) {
  __shared__ float t[32][33];
  int bx = blockIdx.x * 32, by = blockIdx.y * 32;
  int x = threadIdx.x, y = threadIdx.y;
#pragma unroll
  for (int i = 0; i < 32; i += 8) t[y + i][x] = in[(size_t)(by + y + i) * C + bx + x];
  __syncthreads();
#pragma unroll
  for (int i = 0; i < 32; i += 8) out[(size_t)(bx + y + i) * R + by + x] = f2b(t[x][y + i]);
}

// ------------------------------------------------- per-point MLP + scatter max
// wave-per-point: lane k owns hidden feature k (H=64). LN over 64 lanes via
// shfl reductions; 64x64 matmul via readlane broadcast + per-lane w2 column.
__global__ __launch_bounds__(256) void point_mlp_scatter(
    const float* __restrict__ x, const int* __restrict__ idx, int P,
    const float* __restrict__ w1, const float* __restrict__ b1,
    const float* __restrict__ g1, const float* __restrict__ be1,
    const float* __restrict__ w2, const float* __restrict__ b2,
    unsigned* __restrict__ xgU) {
  int lane = threadIdx.x & 63;
  float w1c0 = w1[lane];
  float w1c1 = w1[64 + lane];
  float w1c2 = w1[128 + lane];
  float b1l = b1[lane];
  float g1l = g1[lane];
  float be1l = be1[lane];
  float b2l = b2[lane];
  float w2col[64];
#pragma unroll
  for (int k = 0; k < 64; k++) w2col[k] = w2[k * 64 + lane];  // w2[k][lane]

  int wid = (blockIdx.x * blockDim.x + threadIdx.x) >> 6;
  int nw = (gridDim.x * blockDim.x) >> 6;
  for (int p = wid; p < P; p += nw) {
    float x0 = x[3 * p], x1 = x[3 * p + 1], x2 = x[3 * p + 2];
    float h = fmaf(x0, w1c0, fmaf(x1, w1c1, fmaf(x2, w1c2, b1l)));
    float s = h, q = h * h;
#pragma unroll
    for (int off = 32; off > 0; off >>= 1) {
      s += __shfl_xor(s, off, 64);
      q += __shfl_xor(q, off, 64);
    }
    float m = s * (1.0f / 64.0f);
    float v = fmaf(-m, m, q * (1.0f / 64.0f));
    float hn = (h - m) * rsqrtf(v + EPS) * g1l + be1l;
    hn = fmaxf(hn, 0.0f);
    float a0 = 0.f, a1 = 0.f, a2 = 0.f, a3 = 0.f;
#pragma unroll
    for (int k = 0; k < 64; k += 4) {
      a0 = fmaf(__int_as_float(__builtin_amdgcn_readlane(__float_as_int(hn), k + 0)), w2col[k + 0], a0);
      a1 = fmaf(__int_as_float(__builtin_amdgcn_readlane(__float_as_int(hn), k + 1)), w2col[k + 1], a1);
      a2 = fmaf(__int_as_float(__builtin_amdgcn_readlane(__float_as_int(hn), k + 2)), w2col[k + 2], a2);
      a3 = fmaf(__int_as_float(__builtin_amdgcn_readlane(__float_as_int(hn), k + 3)), w2col[k + 3], a3);
    }
    float acc = b2l + ((a0 + a1) + (a2 + a3));
    // monotone ordered-u32 encoding: any finite float encodes > 0, so 0 == empty
    unsigned u = __float_as_uint(acc);
    unsigned ord = (u & 0x80000000u) ? ~u : (u | 0x80000000u);
    int node = idx[p];
    atomicMax(&xgU[node * 64 + lane], ord);
  }
}

// ------------------------------------------------------- decode max -> bf16
__global__ __launch_bounds__(256) void finalize_xg(const unsigned* __restrict__ xgU,
                                                   unsigned short* __restrict__ xgB, int n) {
  int i = blockIdx.x * blockDim.x + threadIdx.x;
  if (i >= n) return;
  unsigned u = xgU[i];
  float f;
  if (u == 0u) f = 0.0f;  // empty segment
  else if (u & 0x80000000u) f = __uint_as_float(u ^ 0x80000000u);
  else f = __uint_as_float(~u);
  xgB[i] = f2b(f);
}

// ------------------------------------------------------------- MFMA GEMM
// C[m, colOff+n] = bf16( sum_k A[m,k]*BT[n,k] + bias[n] ), bias (f32) nullable.
__global__ __launch_bounds__(256) void gemm_bt(
    const unsigned short* __restrict__ A, int lda,
    const unsigned short* __restrict__ BT, int ldb,
    const float* __restrict__ bias,
    unsigned short* __restrict__ C, int ldc, int colOff, int K) {
  __shared__ __align__(16) unsigned short As[128 * 32];
  __shared__ __align__(16) unsigned short Bs[128 * 32];
  int tid = threadIdx.x;
  int m0 = blockIdx.y * 128, n0 = blockIdx.x * 128;
  int lane = tid & 63, w = tid >> 6;
  int wm = (w >> 1) * 64, wn = (w & 1) * 64;
  int lr = lane & 15, quad = lane >> 4;
  floatx4 acc[4][4] = {};

  for (int k0 = 0; k0 < K; k0 += 32) {
    __syncthreads();
#pragma unroll
    for (int s = 0; s < 2; s++) {
      int cc = tid + s * 256;
      int row = cc >> 2, kc = (cc & 3) << 3;
      *reinterpret_cast<uint4*>(&As[row * 32 + kc]) =
          *reinterpret_cast<const uint4*>(&A[(size_t)(m0 + row) * lda + k0 + kc]);
      *reinterpret_cast<uint4*>(&Bs[row * 32 + kc]) =
          *reinterpret_cast<const uint4*>(&BT[(size_t)(n0 + row) * ldb + k0 + kc]);
    }
    __syncthreads();
    bf16x8 a[4], b[4];
#pragma unroll
    for (int i = 0; i < 4; i++)
      a[i] = *reinterpret_cast<const bf16x8*>(&As[(wm + i * 16 + lr) * 32 + quad * 8]);
#pragma unroll
    for (int j = 0; j < 4; j++)
      b[j] = *reinterpret_cast<const bf16x8*>(&Bs[(wn + j * 16 + lr) * 32 + quad * 8]);
#pragma unroll
    for (int i = 0; i < 4; i++)
#pragma unroll
      for (int j = 0; j < 4; j++)
        acc[i][j] = __builtin_amdgcn_mfma_f32_16x16x32_bf16(a[i], b[j], acc[i][j], 0, 0, 0);
  }
#pragma unroll
  for (int j = 0; j < 4; j++) {
    int gcol = n0 + wn + j * 16 + lr;
    float bv = bias ? bias[gcol] : 0.0f;
#pragma unroll
    for (int i = 0; i < 4; i++) {
#pragma unroll
      for (int r = 0; r < 4; r++) {
        int grow = m0 + wm + i * 16 + quad * 4 + r;
        C[(size_t)grow * ldc + colOff + gcol] = f2b(acc[i][j][r] + bv);
      }
    }
  }
}

// ----------------------- fused final GEMM: virtual K=2048 over 3 A sources
// A0=t_pos[NN,768] bf16, A1=t_aff[NN,768] bf16, A2=x_sem[NN,512] f32 (packed
// to bf16 in the stager); BT=BTcat[768,2048] bf16; bias f32; out F bf16.
__global__ __launch_bounds__(256) void gemm_fuse3(
    const unsigned short* __restrict__ A0, const unsigned short* __restrict__ A1,
    const float* __restrict__ A2f, const unsigned short* __restrict__ BT,
    const float* __restrict__ bias, unsigned short* __restrict__ C) {
  __shared__ __align__(16) unsigned short As[128 * 32];
  __shared__ __align__(16) unsigned short Bs[128 * 32];
  int tid = threadIdx.x;
  int m0 = blockIdx.y * 128, n0 = blockIdx.x * 128;
  int lane = tid & 63, w = tid >> 6;
  int wm = (w >> 1) * 64, wn = (w & 1) * 64;
  int lr = lane & 15, quad = lane >> 4;
  floatx4 acc[4][4] = {};

  for (int k0 = 0; k0 < 2048; k0 += 32) {
    __syncthreads();
    if (k0 < 1536) {
      const unsigned short* Ap = (k0 < 768) ? A0 : A1;
      int kk = (k0 < 768) ? k0 : (k0 - 768);
#pragma unroll
      for (int s = 0; s < 2; s++) {
        int cc = tid + s * 256;
        int row = cc >> 2, kc = (cc & 3) << 3;
        *reinterpret_cast<uint4*>(&As[row * 32 + kc]) =
            *reinterpret_cast<const uint4*>(&Ap[(size_t)(m0 + row) * 768 + kk + kc]);
      }
    } else {
      int kk = k0 - 1536;
#pragma unroll
      for (int s = 0; s < 2; s++) {
        int cc = tid + s * 256;
        int row = cc >> 2, kc = (cc & 3) << 3;
        const float* src = &A2f[(size_t)(m0 + row) * 512 + kk + kc];
        float4 fa = *reinterpret_cast<const float4*>(src);
        float4 fb = *reinterpret_cast<const float4*>(src + 4);
        uint4 pk;
        pk.x = (unsigned)f2b(fa.x) | ((unsigned)f2b(fa.y) << 16);
        pk.y = (unsigned)f2b(fa.z) | ((unsigned)f2b(fa.w) << 16);
        pk.z = (unsigned)f2b(fb.x) | ((unsigned)f2b(fb.y) << 16);
        pk.w = (unsigned)f2b(fb.z) | ((unsigned)f2b(fb.w) << 16);
        *reinterpret_cast<uint4*>(&As[row * 32 + kc]) = pk;
      }
    }
#pragma unroll
    for (int s = 0; s < 2; s++) {
      int cc = tid + s * 256;
      int row = cc >> 2, kc = (cc & 3) << 3;
      *reinterpret_cast<uint4*>(&Bs[row * 32 + kc]) =
          *reinterpret_cast<const uint4*>(&BT[(size_t)(n0 + row) * 2048 + k0 + kc]);
    }
    __syncthreads();
    bf16x8 a[4], b[4];
#pragma unroll
    for (int i = 0; i < 4; i++)
      a[i] = *reinterpret_cast<const bf16x8*>(&As[(wm + i * 16 + lr) * 32 + quad * 8]);
#pragma unroll
    for (int j = 0; j < 4; j++)
      b[j] = *reinterpret_cast<const bf16x8*>(&Bs[(wn + j * 16 + lr) * 32 + quad * 8]);
#pragma unroll
    for (int i = 0; i < 4; i++)
#pragma unroll
      for (int j = 0; j < 4; j++)
        acc[i][j] = __builtin_amdgcn_mfma_f32_16x16x32_bf16(a[i], b[j], acc[i][j], 0, 0, 0);
  }
#pragma unroll
  for (int j = 0; j < 4; j++) {
    int gcol = n0 + wn + j * 16 + lr;
    float bv = bias[gcol];
#pragma unroll
    for (int i = 0; i < 4; i++) {
#pragma unroll
      for (int r = 0; r < 4; r++) {
        int grow = m0 + wm + i * 16 + quad * 4 + r;
        C[(size_t)grow * 768 + gcol] = f2b(acc[i][j][r] + bv);
      }
    }
  }
}

// ------------- fold all upstream biases into the fusion bias (f32 in/out)
__global__ __launch_bounds__(256) void fuse_bias(
    const float* __restrict__ fus_b, const float* __restrict__ fus_w,
    const float* __restrict__ pb4, const float* __restrict__ ab4,
    const float* __restrict__ semb, float* __restrict__ bias_tot) {
  int c = blockIdx.x;  // 768
  int tid = threadIdx.x;
  float s = 0.f;
  for (int j = tid; j < 768; j += 256) {
    s = fmaf(pb4[j],  fus_w[(size_t)j * 768 + c], s);
    s = fmaf(ab4[j],  fus_w[(size_t)(768 + j) * 768 + c], s);
    s = fmaf(semb[j], fus_w[(size_t)(1536 + j) * 768 + c], s);
  }
#pragma unroll
  for (int off = 32; off > 0; off >>= 1) s += __shfl_xor(s, off, 64);
  __shared__ float sm[4];
  if ((tid & 63) == 0) sm[tid >> 6] = s;
  __syncthreads();
  if (tid == 0) bias_tot[c] = sm[0] + sm[1] + sm[2] + sm[3] + fus_b[c];
}

// ------------------------------------- rowwise LN(768)+ReLU, bf16 in/bf16 out
__global__ __launch_bounds__(256) void ln_relu_768_b16(
    const unsigned short* __restrict__ X, const float* __restrict__ g,
    const float* __restrict__ be, unsigned short* __restrict__ Y) {
  int row = blockIdx.x, tid = threadIdx.x;
  size_t base = (size_t)row * 768;
  float xv[3];
#pragma unroll
  for (int i = 0; i < 3; i++) xv[i] = b2f(X[base + tid + i * 256]);
  float s = xv[0] + xv[1] + xv[2];
  float q = xv[0] * xv[0] + xv[1] * xv[1] + xv[2] * xv[2];
#pragma unroll
  for (int off = 32; off > 0; off >>= 1) {
    s += __shfl_xor(s, off, 64);
    q += __shfl_xor(q, off, 64);
  }
  __shared__ float ss[4], qq[4];
  int w = tid >> 6, lane = tid & 63;
  if (lane == 0) { ss[w] = s; qq[w] = q; }
  __syncthreads();
  s = ss[0] + ss[1] + ss[2] + ss[3];
  q = qq[0] + qq[1] + qq[2] + qq[3];
  float m = s * (1.0f / 768.0f);
  float v = fmaf(-m, m, q * (1.0f / 768.0f));
  float rstd = rsqrtf(v + EPS);
#pragma unroll
  for (int i = 0; i < 3; i++) {
    int c = tid + i * 256;
    float y = (xv[i] - m) * rstd * g[c] + be[c];
    Y[base + c] = f2b(fmaxf(y, 0.0f));
  }
}

// ------------------------------------- rowwise LN(768)+ReLU, bf16 in/f32 out
__global__ __launch_bounds__(256) void ln_relu_768_f32(
    const unsigned short* __restrict__ X, const float* __restrict__ g,
    const float* __restrict__ be, float* __restrict__ Y) {
  int row = blockIdx.x, tid = threadIdx.x;
  size_t base = (size_t)row * 768;
  float xv[3];
#pragma unroll
  for (int i = 0; i < 3; i++) xv[i] = b2f(X[base + tid + i * 256]);
  float s = xv[0] + xv[1] + xv[2];
  float q = xv[0] * xv[0] + xv[1] * xv[1] + xv[2] * xv[2];
#pragma unroll
  for (int off = 32; off > 0; off >>= 1) {
    s += __shfl_xor(s, off, 64);
    q += __shfl_xor(q, off, 64);
  }
  __shared__ float ss[4], qq[4];
  int w = tid >> 6, lane = tid & 63;
  if (lane == 0) { ss[w] = s; qq[w] = q; }
  __syncthreads();
  s = ss[0] + ss[1] + ss[2] + ss[3];
  q = qq[0] + qq[1] + qq[2] + qq[3];
  float m = s * (1.0f / 768.0f);
  float v = fmaf(-m, m, q * (1.0f / 768.0f));
  float rstd = rsqrtf(v + EPS);
#pragma unroll
  for (int i = 0; i < 3; i++) {
    int c = tid + i * 256;
    float y = (xv[i] - m) * rstd * g[c] + be[c];
    Y[base + c] = fmaxf(y, 0.0f);
  }
}

extern "C" void kernel_launch(void* const* d_in, const int* in_sizes, int n_in,
                              void* d_out, int out_size, void* d_ws, size_t ws_size,
                              hipStream_t stream) {
  typedef const float* cf;
  cf x_pos = (cf)d_in[0];
  const int* pos_idx = (const int*)d_in[1];
  cf x_aff = (cf)d_in[2];
  const int* aff_idx = (const int*)d_in[3];
  cf x_sem = (cf)d_in[4];
  cf pw1 = (cf)d_in[6],  pb1 = (cf)d_in[7],  pg1 = (cf)d_in[8],  pbe1 = (cf)d_in[9];
  cf pw2 = (cf)d_in[10], pb2 = (cf)d_in[11];
  cf pw3 = (cf)d_in[12], pb3 = (cf)d_in[13], pg2 = (cf)d_in[14], pbe2 = (cf)d_in[15];
  cf pw4 = (cf)d_in[16], pb4 = (cf)d_in[17];
  cf aw1 = (cf)d_in[18], ab1 = (cf)d_in[19], ag1 = (cf)d_in[20], abe1 = (cf)d_in[21];
  cf aw2 = (cf)d_in[22], ab2 = (cf)d_in[23];
  cf aw3 = (cf)d_in[24], ab3 = (cf)d_in[25], ag2 = (cf)d_in[26], abe2 = (cf)d_in[27];
  cf aw4 = (cf)d_in[28], ab4 = (cf)d_in[29];
  cf semw = (cf)d_in[30], semb = (cf)d_in[31];
  cf fusw = (cf)d_in[32], fusb = (cf)d_in[33], fusg = (cf)d_in[34], fusbe = (cf)d_in[35];

  int P = in_sizes[0] / 3;

  char* wsb = (char*)d_ws;
  size_t off = 0;
  auto carve = [&](size_t bytes) -> void* {
    void* p = wsb + off;
    off = (off + bytes + 255) & ~(size_t)255;
    return p;
  };
  unsigned* xgU = (unsigned*)carve((size_t)2 * NN * 64 * 4);              // 8 MiB
  unsigned* xgU_pos = xgU;
  unsigned* xgU_aff = xgU + (size_t)NN * 64;
  unsigned short* xgB = (unsigned short*)carve((size_t)2 * NN * 64 * 2);  // 4 MiB
  unsigned short* xgB_pos = xgB;
  unsigned short* xgB_aff = xgB + (size_t)NN * 64;
  unsigned short* t_pos = (unsigned short*)carve((size_t)NN * 768 * 2);   // 24 MiB
  unsigned short* t_aff = (unsigned short*)carve((size_t)NN * 768 * 2);   // 24 MiB
  unsigned short* F     = (unsigned short*)carve((size_t)NN * 768 * 2);   // 24 MiB
  unsigned short* w3T_pos = (unsigned short*)carve((size_t)768 * 64 * 2);
  unsigned short* w3T_aff = (unsigned short*)carve((size_t)768 * 64 * 2);
  unsigned short* fusT  = (unsigned short*)carve((size_t)768 * 2304 * 2); // 3.4 MiB
  unsigned short* pw4B  = (unsigned short*)carve((size_t)768 * 768 * 2);
  unsigned short* aw4B  = (unsigned short*)carve((size_t)768 * 768 * 2);
  unsigned short* semwB = (unsigned short*)carve((size_t)512 * 768 * 2);
  unsigned short* BTcat = (unsigned short*)carve((size_t)768 * 2048 * 2); // 3 MiB
  float* bias_tot = (float*)carve((size_t)768 * 4);
  // total ~94 MiB

  int nz = 2 * NN * 64;
  zero_u32<<<(nz + 255) / 256, 256, 0, stream>>>(xgU, nz);

  // weight prep: transposes + bf16 casts
  dim3 tb(32, 8);
  transpose_f32_b16<<<dim3(24, 2),  tb, 0, stream>>>(pw3, w3T_pos, 64, 768);
  transpose_f32_b16<<<dim3(24, 2),  tb, 0, stream>>>(aw3, w3T_aff, 64, 768);
  transpose_f32_b16<<<dim3(24, 72), tb, 0, stream>>>(fusw, fusT, 2304, 768);
  convert_f32_b16<<<(768 * 768 + 255) / 256, 256, 0, stream>>>(pw4, pw4B, 768 * 768);
  convert_f32_b16<<<(768 * 768 + 255) / 256, 256, 0, stream>>>(aw4, aw4B, 768 * 768);
  convert_f32_b16<<<(512 * 768 + 255) / 256, 256, 0, stream>>>(semw, semwB, 512 * 768);

  // weight folds: BTcat[c, 0:768] = (pw4@fusW1)^T etc., stored as BT layout
  gemm_bt<<<dim3(6, 6), 256, 0, stream>>>(fusT,        2304, pw4B,  768, nullptr, BTcat, 2048, 0,    768);
  gemm_bt<<<dim3(6, 6), 256, 0, stream>>>(fusT + 768,  2304, aw4B,  768, nullptr, BTcat, 2048, 768,  768);
  gemm_bt<<<dim3(4, 6), 256, 0, stream>>>(fusT + 1536, 2304, semwB, 768, nullptr, BTcat, 2048, 1536, 768);
  fuse_bias<<<768, 256, 0, stream>>>(fusb, fusw, pb4, ab4, semb, bias_tot);

  // point branches
  point_mlp_scatter<<<2048, 256, 0, stream>>>(x_pos, pos_idx, P, pw1, pb1, pg1, pbe1, pw2, pb2, xgU_pos);
  point_mlp_scatter<<<2048, 256, 0, stream>>>(x_aff, aff_idx, P, aw1, ab1, ag1, abe1, aw2, ab2, xgU_aff);
  finalize_xg<<<(nz + 255) / 256, 256, 0, stream>>>(xgU, xgB, nz);

  // mlp2 first linear + LN + ReLU
  gemm_bt<<<dim3(6, NN / 128), 256, 0, stream>>>(xgB_pos, 64, w3T_pos, 64, pb3, t_pos, 768, 0, 64);
  gemm_bt<<<dim3(6, NN / 128), 256, 0, stream>>>(xgB_aff, 64, w3T_aff, 64, ab3, t_aff, 768, 0, 64);
  ln_relu_768_b16<<<NN, 256, 0, stream>>>(t_pos, pg2, pbe2, t_pos);
  ln_relu_768_b16<<<NN, 256, 0, stream>>>(t_aff, ag2, abe2, t_aff);

  // fused final GEMM (w4/sem/fusion folded), then LN+ReLU -> f32 out
  gemm_fuse3<<<dim3(6, NN / 128), 256, 0, stream>>>(t_pos, t_aff, x_sem, BTcat, bias_tot, F);
  ln_relu_768_f32<<<NN, 256, 0, stream>>>(F, fusg, fusbe, (float*)d_out);
}